// Round 15
// baseline (120.190 us; speedup 1.0000x reference)
//
#include <hip/hip_runtime.h>

typedef unsigned short u16;
typedef __bf16 bf16x8 __attribute__((ext_vector_type(8)));
typedef float f32x4 __attribute__((ext_vector_type(4)));
typedef u16 u16x8 __attribute__((ext_vector_type(8)));

#define NSPLIT 11            // attention: 4224 keys = 11 splits * 6 * 64
#define ANBLK 6
#define KSPLIT 4             // qkv GEMM K-splits
#define OSPLIT 8             // oproj K-splits
#define SCALE_Q 0.08838834764831843f   // 1/sqrt(128), folded into q

__device__ __forceinline__ u16 f2bf(float f) {
    unsigned u = __builtin_bit_cast(unsigned, f);
    u += 0x7fff + ((u >> 16) & 1);     // RNE
    return (u16)(u >> 16);
}
__device__ __forceinline__ float bf2f(u16 h) {
    unsigned u = ((unsigned)h) << 16;
    return __builtin_bit_cast(float, u);
}
__device__ __forceinline__ f32x4 mfma16(bf16x8 a, bf16x8 b, f32x4 c) {
    return __builtin_amdgcn_mfma_f32_16x16x32_bf16(a, b, c, 0, 0, 0);
}

// ------ Kernel 0: pre-pack c=[x_ctx;x] as bf16 MFMA A-fragments (1 MB) ------
__global__ __launch_bounds__(256)
void k_prep(const float* __restrict__ x, const float* __restrict__ xctx,
            u16* __restrict__ fragA)
{
    int tid = blockIdx.x * 256 + threadIdx.x;   // 65536 threads
    int row = tid >> 9;
    int k0 = (tid & 511) << 3;
    const float* src = (row < 64) ? (xctx + (size_t)row * 4096)
                                  : (x + (size_t)(row - 64) * 4096);
    f32x4 v0 = *(const f32x4*)&src[k0];
    f32x4 v1 = *(const f32x4*)&src[k0 + 4];
    u16x8 o;
    o[0] = f2bf(v0[0]); o[1] = f2bf(v0[1]); o[2] = f2bf(v0[2]); o[3] = f2bf(v0[3]);
    o[4] = f2bf(v1[0]); o[5] = f2bf(v1[1]); o[6] = f2bf(v1[2]); o[7] = f2bf(v1[3]);
    int ks32 = k0 >> 5;
    int lg = (k0 >> 3) & 3;
    int rt = row >> 4;
    int l = lg * 16 + (row & 15);
    *(u16x8*)&fragA[(((size_t)ks32 * 8 + rt) * 64 + l) * 8] = o;
}

// ------ Kernel 1: QKV projection, split-K, register-ring (R11 config) -------
template<int KS>
__global__ __launch_bounds__(256)
void k_qkv(const u16* __restrict__ fragA,
           const float* __restrict__ Wq, const float* __restrict__ Wk,
           const float* __restrict__ Wv, float* __restrict__ part)
{
    constexpr int KCk = 4096 / KS;
    constexpr int NKT = KCk / 64;
    const int col0 = blockIdx.x * 32;
    const int ksp = blockIdx.y;
    const int ks0 = ksp * KCk;
    const float* W; int ldw, cbase, mat;
    if (col0 < 4096)      { W = Wq; ldw = 4096; cbase = col0;        mat = 0; }
    else if (col0 < 5120) { W = Wk; ldw = 1024; cbase = col0 - 4096; mat = 1; }
    else                  { W = Wv; ldw = 1024; cbase = col0 - 5120; mat = 2; }
    const bool full = (mat != 0);
    const int rowbase = full ? 0 : 64;

    __shared__ __align__(16) u16 Bs[2][32 * 64];

    const int t = threadIdx.x;
    const int w = t >> 6, l = t & 63;
    const int lm = l & 15, lg = l >> 4;
    const int bk = (t >> 3) << 1;
    const int bn4 = (t & 7) << 2;

    f32x4 pb[4][2];
    bf16x8 af[2][4];
    f32x4 acc[2][2] = {};
    const int rt0 = full ? (w * 2) : (4 + w);

    #define QKV_BLOAD(slot_, kt_)                                              \
    {                                                                          \
        const int kg = ks0 + (kt_) * 64;                                       \
        pb[slot_][0] = *(const f32x4*)&W[(size_t)(kg + bk) * ldw + cbase + bn4]; \
        pb[slot_][1] = *(const f32x4*)&W[(size_t)(kg + bk + 1) * ldw + cbase + bn4]; \
    }
    #define QKV_BSTORE(buf_, slot_)                                            \
    {                                                                          \
        _Pragma("unroll")                                                      \
        for (int j = 0; j < 4; j++) {                                          \
            int n = bn4 + j;                                                   \
            int idx = n * 64 + (bk ^ (((n >> 1) & 7) << 3));                   \
            ushort2 v2; v2.x = f2bf(pb[slot_][0][j]); v2.y = f2bf(pb[slot_][1][j]); \
            *(ushort2*)&Bs[buf_][idx] = v2;                                    \
        }                                                                      \
    }
    #define QKV_ALOAD(p_, kt_)                                                 \
    {                                                                          \
        const int kb32 = (ks0 >> 5) + (kt_) * 2;                               \
        af[p_][0] = *(const bf16x8*)&fragA[(((size_t)kb32 * 8 + rt0) * 64 + l) * 8]; \
        af[p_][1] = *(const bf16x8*)&fragA[(((size_t)(kb32 + 1) * 8 + rt0) * 64 + l) * 8]; \
        if (full) {                                                            \
            af[p_][2] = *(const bf16x8*)&fragA[(((size_t)kb32 * 8 + rt0 + 1) * 64 + l) * 8]; \
            af[p_][3] = *(const bf16x8*)&fragA[(((size_t)(kb32 + 1) * 8 + rt0 + 1) * 64 + l) * 8]; \
        }                                                                      \
    }

    QKV_BLOAD(0, 0);
    QKV_BLOAD(1, 1);
    QKV_BLOAD(2, 2);
    QKV_BLOAD(3, 3);
    QKV_ALOAD(0, 0);
    QKV_BSTORE(0, 0);
    __syncthreads();

    #pragma unroll
    for (int kt = 0; kt < NKT; kt++) {
        const int cur = kt & 1;
        if (kt + 4 < NKT) QKV_BLOAD(kt & 3, kt + 4);
        if (kt + 1 < NKT) QKV_ALOAD((kt + 1) & 1, kt + 1);
        if (kt + 1 < NKT) QKV_BSTORE(cur ^ 1, (kt + 1) & 3);
        #pragma unroll
        for (int ks = 0; ks < 2; ks++) {
            const int koff = ks * 32 + lg * 8;
            bf16x8 bfr[2];
            #pragma unroll
            for (int nt = 0; nt < 2; nt++) {
                int n = nt * 16 + lm;
                bfr[nt] = *(const bf16x8*)
                    &Bs[cur][n * 64 + (koff ^ (((n >> 1) & 7) << 3))];
            }
            acc[0][0] = mfma16(af[cur][ks], bfr[0], acc[0][0]);
            acc[0][1] = mfma16(af[cur][ks], bfr[1], acc[0][1]);
            if (full) {
                acc[1][0] = mfma16(af[cur][2 + ks], bfr[0], acc[1][0]);
                acc[1][1] = mfma16(af[cur][2 + ks], bfr[1], acc[1][1]);
            }
        }
        if (kt + 1 < NKT) __syncthreads();
    }

    const int wrows = full ? 32 : 16;
    const int mts = full ? 2 : 1;
    #pragma unroll
    for (int mt = 0; mt < 2; mt++) {
        if (mt >= mts) break;
        #pragma unroll
        for (int nt = 0; nt < 2; nt++)
            #pragma unroll
            for (int r = 0; r < 4; r++) {
                int grow = rowbase + w * wrows + mt * 16 + lg * 4 + r;
                part[((size_t)ksp * 128 + grow) * 6144 + col0 + nt * 16 + lm] =
                    acc[mt][nt][r];
            }
    }
    #undef QKV_BLOAD
    #undef QKV_BSTORE
    #undef QKV_ALOAD
}

// ------- Kernel 2: partial-sum + RMSNorm + RoPE (q, k) + v passthrough ------
template<int KS>
__global__ __launch_bounds__(256)
void k_normrope(const float* __restrict__ part,
                const float* __restrict__ cosq, const float* __restrict__ sinq,
                const float* __restrict__ cosk, const float* __restrict__ sink,
                const float* __restrict__ qnw, const float* __restrict__ knw,
                u16* __restrict__ qb, u16* __restrict__ kb,
                float* __restrict__ outk, float* __restrict__ outv,
                u16* __restrict__ vbw)
{
    int wid = blockIdx.x * 4 + (threadIdx.x >> 6);
    int lane = threadIdx.x & 63;
    if (wid < 2048) {                          // q: (h, l)
        int h = wid >> 6, lq = wid & 63;
        size_t ro = (size_t)(64 + lq) * 6144 + h * 128;
        float x1 = 0.f, x2 = 0.f;
        #pragma unroll
        for (int s = 0; s < KS; s++) {
            x1 += part[(size_t)s * 786432 + ro + lane];
            x2 += part[(size_t)s * 786432 + ro + lane + 64];
        }
        float ss = x1 * x1 + x2 * x2;
        #pragma unroll
        for (int off = 32; off; off >>= 1) ss += __shfl_xor(ss, off);
        float rms = rsqrtf(ss * (1.0f / 128.0f) + 1e-6f);
        float a = x1 * rms * qnw[lane];
        float b = x2 * rms * qnw[lane + 64];
        float c = cosq[lq * 64 + lane], s = sinq[lq * 64 + lane];
        u16* qo = qb + ((size_t)h * 64 + lq) * 128;
        qo[lane]      = f2bf((a * c - b * s) * SCALE_Q);
        qo[lane + 64] = f2bf((b * c + a * s) * SCALE_Q);
    } else if (wid < 3072) {                   // k: (kh, t)
        int rr = wid - 2048;
        int kh = rr >> 7, tt = rr & 127;
        size_t ro = (size_t)tt * 6144 + 4096 + kh * 128;
        float x1 = 0.f, x2 = 0.f;
        #pragma unroll
        for (int s = 0; s < KS; s++) {
            x1 += part[(size_t)s * 786432 + ro + lane];
            x2 += part[(size_t)s * 786432 + ro + lane + 64];
        }
        float ss = x1 * x1 + x2 * x2;
        #pragma unroll
        for (int off = 32; off; off >>= 1) ss += __shfl_xor(ss, off);
        float rms = rsqrtf(ss * (1.0f / 128.0f) + 1e-6f);
        float a = x1 * rms * knw[lane];
        float b = x2 * rms * knw[lane + 64];
        float c = cosk[tt * 64 + lane], s = sink[tt * 64 + lane];
        float o1 = a * c - b * s, o2 = b * c + a * s;
        size_t oi = ((size_t)kh * 128 + tt) * 128;
        outk[oi + lane] = o1; outk[oi + lane + 64] = o2;   // output 1 (k), f32
        kb[oi + lane] = f2bf(o1); kb[oi + lane + 64] = f2bf(o2);
    } else {                                   // v: (kh, t) partial sum only
        int rr = wid - 3072;
        int kh = rr >> 7, tt = rr & 127;
        size_t ro = (size_t)tt * 6144 + 5120 + kh * 128;
        float v1 = 0.f, v2 = 0.f;
        #pragma unroll
        for (int s = 0; s < KS; s++) {
            v1 += part[(size_t)s * 786432 + ro + lane];
            v2 += part[(size_t)s * 786432 + ro + lane + 64];
        }
        size_t oi = ((size_t)kh * 128 + tt) * 128;
        outv[oi + lane] = v1; outv[oi + lane + 64] = v2;   // output 2 (v), f32
        vbw[oi + lane] = f2bf(v1); vbw[oi + lane + 64] = f2bf(v2);
    }
}

// ------ Kernel 2.5: build bf16 kcache[kh][4224][128] + vcacheT[kh][128][4224]
__global__ __launch_bounds__(256)
void k_prepkv(const float* __restrict__ cacheK, const float* __restrict__ cacheV,
              const u16* __restrict__ kb, const u16* __restrict__ vb,
              u16* __restrict__ kc, u16* __restrict__ vt)
{
    const int bx = blockIdx.x;
    const int t = threadIdx.x;
    if (bx < 528) {                            // V^T tiles
        __shared__ __align__(16) u16 Ls[64][132];
        int kh = bx / 66, tile = bx % 66;
        int key0 = tile * 64;
        #pragma unroll
        for (int it = 0; it < 8; it++) {
            int fidx = it * 256 + t;
            int row = fidx >> 5;
            int d4 = (fidx & 31) << 2;
            int key = key0 + row;
            ushort4 sv;
            if (key < 4096) {
                float4 v = *(const float4*)&cacheV[((size_t)kh * 8192 + key) * 128 + d4];
                sv.x = f2bf(v.x); sv.y = f2bf(v.y); sv.z = f2bf(v.z); sv.w = f2bf(v.w);
            } else {
                sv = *(const ushort4*)&vb[((size_t)kh * 128 + (key - 4096)) * 128 + d4];
            }
            *(ushort4*)&Ls[row][d4] = sv;
        }
        __syncthreads();
        #pragma unroll
        for (int it = 0; it < 4; it++) {
            int fidx = it * 256 + t;
            int d = fidx >> 3;
            int kc8 = (fidx & 7) << 3;
            u16x8 o;
            #pragma unroll
            for (int j = 0; j < 8; j++) o[j] = Ls[kc8 + j][d];
            *(u16x8*)&vt[((size_t)kh * 128 + d) * 4224 + key0 + kc8] = o;
        }
    } else {                                   // K copy/convert
        size_t cidx = (size_t)(bx - 528) * 256 + t;
        int kh = (int)(cidx / 67584);
        int rem = (int)(cidx % 67584);
        int tt = rem >> 4;
        int d8 = (rem & 15) << 3;
        u16x8 o;
        if (tt < 4096) {
            const float* src = &cacheK[((size_t)kh * 8192 + tt) * 128 + d8];
            f32x4 a = *(const f32x4*)src;
            f32x4 b = *(const f32x4*)(src + 4);
            o[0] = f2bf(a[0]); o[1] = f2bf(a[1]); o[2] = f2bf(a[2]); o[3] = f2bf(a[3]);
            o[4] = f2bf(b[0]); o[5] = f2bf(b[1]); o[6] = f2bf(b[2]); o[7] = f2bf(b[3]);
        } else {
            o = *(const u16x8*)&kb[((size_t)kh * 128 + (tt - 4096)) * 128 + d8];
        }
        *(u16x8*)&kc[((size_t)kh * 4224 + tt) * 128 + d8] = o;
    }
}

// --------- Kernel 3: split-K flash attention (no-max online softmax) --------
__global__ __launch_bounds__(256)
void k_attn(const u16* __restrict__ qb, const u16* __restrict__ kcache,
            const u16* __restrict__ vcacheT,
            u16* __restrict__ opart, float* __restrict__ lpart)
{
    const int split = blockIdx.x;
    const int kh = blockIdx.y;
    const int z = blockIdx.z;
    const int t = threadIdx.x;
    const int w = t >> 6, l = t & 63;
    const int lm = l & 15, lg = l >> 4;
    const int rep = z * 2 + (w >> 1);
    const int mh = w & 1;

    __shared__ __align__(16) u16 Ks[64][136];
    __shared__ __align__(16) u16 Vs[128][72];
    __shared__ __align__(16) u16 Ps[4][32][40];

    const u16* qh = qb + ((size_t)(kh * 4 + rep) * 64) * 128;
    bf16x8 aq[2][4];
    #pragma unroll
    for (int mt = 0; mt < 2; mt++)
        #pragma unroll
        for (int ks = 0; ks < 4; ks++)
            aq[mt][ks] = *(const bf16x8*)
                &qh[(size_t)(mh * 32 + mt * 16 + lm) * 128 + ks * 32 + lg * 8];

    const u16* kcb = kcache + (size_t)kh * 4224 * 128;
    const u16* vtb = vcacheT + (size_t)kh * 128 * 4224;

    const int krow = t >> 4;
    const int kdc = (t & 15) << 3;
    const int vd = t >> 3;
    const int vkc = t & 7;

    u16x8 pk[4], pv[4];
    f32x4 accO[2][8] = {};
    float lacc[2][4] = {};

    #define AT_LOAD(key0_)                                                     \
    {                                                                          \
        _Pragma("unroll")                                                      \
        for (int it = 0; it < 4; it++)                                         \
            pk[it] = *(const u16x8*)&kcb[(size_t)((key0_) + it * 16 + krow) * 128 + kdc]; \
        _Pragma("unroll")                                                      \
        for (int it = 0; it < 4; it++)                                         \
            pv[it] = *(const u16x8*)&vtb[(size_t)(it * 32 + vd) * 4224 + (key0_) + vkc * 8]; \
    }
    #define AT_STORE()                                                         \
    {                                                                          \
        _Pragma("unroll")                                                      \
        for (int it = 0; it < 4; it++)                                         \
            *(u16x8*)&Ks[it * 16 + krow][kdc] = pk[it];                        \
        _Pragma("unroll")                                                      \
        for (int it = 0; it < 4; it++) {                                       \
            int d = it * 32 + vd;                                              \
            *(u16x8*)&Vs[d][(vkc ^ ((d >> 2) & 7)) << 3] = pv[it];             \
        }                                                                      \
    }

    AT_LOAD(split * (64 * ANBLK));
    #pragma unroll 1
    for (int kbi = 0; kbi < ANBLK; kbi++) {
        __syncthreads();
        AT_STORE();
        __syncthreads();
        if (kbi + 1 < ANBLK) AT_LOAD(split * (64 * ANBLK) + (kbi + 1) * 64);

        f32x4 sa[2][4] = {};
        #pragma unroll
        for (int ks = 0; ks < 4; ks++) {
            bf16x8 bk[4];
            #pragma unroll
            for (int nt = 0; nt < 4; nt++)
                bk[nt] = *(const bf16x8*)&Ks[nt * 16 + lm][ks * 32 + lg * 8];
            #pragma unroll
            for (int mt = 0; mt < 2; mt++)
                #pragma unroll
                for (int nt = 0; nt < 4; nt++)
                    sa[mt][nt] = mfma16(aq[mt][ks], bk[nt], sa[mt][nt]);
        }

        #pragma unroll
        for (int half = 0; half < 2; half++) {
            #pragma unroll
            for (int mt = 0; mt < 2; mt++)
                #pragma unroll
                for (int nt2 = 0; nt2 < 2; nt2++)
                    #pragma unroll
                    for (int r = 0; r < 4; r++) {
                        float e = __expf(sa[mt][half * 2 + nt2][r]);
                        lacc[mt][r] += e;
                        Ps[w][mt * 16 + lg * 4 + r][nt2 * 16 + lm] = f2bf(e);
                    }
            bf16x8 pa[2];
            #pragma unroll
            for (int mt = 0; mt < 2; mt++)
                pa[mt] = *(const bf16x8*)&Ps[w][mt * 16 + lm][lg * 8];
            #pragma unroll
            for (int dt = 0; dt < 8; dt++) {
                int d = dt * 16 + lm;
                int vswz = ((d >> 2) & 7) << 3;
                bf16x8 vb8 = *(const bf16x8*)&Vs[d][(half * 32 + lg * 8) ^ vswz];
                #pragma unroll
                for (int mt = 0; mt < 2; mt++)
                    accO[mt][dt] = mfma16(pa[mt], vb8, accO[mt][dt]);
            }
        }
    }
    #undef AT_LOAD
    #undef AT_STORE

    #pragma unroll
    for (int mt = 0; mt < 2; mt++)
        #pragma unroll
        for (int r = 0; r < 4; r++) {
            float v = lacc[mt][r];
            v += __shfl_xor(v, 1);
            v += __shfl_xor(v, 2);
            v += __shfl_xor(v, 4);
            v += __shfl_xor(v, 8);
            lacc[mt][r] = v;
        }

    const size_t base = (((size_t)kh * NSPLIT + split) * 4 + rep) * 64 + mh * 32;
    if (lm == 0) {
        #pragma unroll
        for (int mt = 0; mt < 2; mt++)
            #pragma unroll
            for (int r = 0; r < 4; r++)
                lpart[base + mt * 16 + lg * 4 + r] = lacc[mt][r];
    }
    #pragma unroll
    for (int mt = 0; mt < 2; mt++)
        #pragma unroll
        for (int dt = 0; dt < 8; dt++)
            #pragma unroll
            for (int r = 0; r < 4; r++)
                opart[(base + mt * 16 + lg * 4 + r) * 128 + dt * 16 + lm] =
                    f2bf(accO[mt][dt][r]);
}

// ---------- Kernel 4: combine splits, normalize (vectorized u16x8) ----------
template<int NSP>
__global__ __launch_bounds__(256)
void k_combine(const u16* __restrict__ opart, const float* __restrict__ lpart,
               u16* __restrict__ obf)
{
    int idx = blockIdx.x * 256 + threadIdx.x;
    int lq = idx >> 9;
    int c8 = (idx & 511) << 3;
    int h = c8 >> 7, d = c8 & 127;
    int kh = h >> 2, rep = h & 3;
    float os[8] = {};
    float ls = 0.f;
    #pragma unroll
    for (int s = 0; s < NSP; s++) {
        size_t b = (((size_t)kh * NSP + s) * 4 + rep) * 64 + lq;
        u16x8 v = *(const u16x8*)&opart[b * 128 + d];
        #pragma unroll
        for (int j = 0; j < 8; j++) os[j] += bf2f(v[j]);
        ls += lpart[b];
    }
    float inv = 1.0f / ls;
    u16x8 o;
    #pragma unroll
    for (int j = 0; j < 8; j++) o[j] = f2bf(os[j] * inv);
    *(u16x8*)&obf[(size_t)lq * 4096 + c8] = o;
}

// ------ Kernel 5: O projection, split-K, 4-deep register-ring (R11) ---------
__global__ __launch_bounds__(256)
void k_oproj(const u16* __restrict__ obf, const float* __restrict__ Wo,
             float* __restrict__ parto)
{
    constexpr int NKT = 4096 / OSPLIT / 64;    // 8
    const int col0 = blockIdx.x * 32;
    const int osp = blockIdx.y;
    const int ks0 = osp * (4096 / OSPLIT);

    __shared__ __align__(16) u16 As[2][64][72];
    __shared__ __align__(16) u16 Bs[2][32 * 64];

    const int t = threadIdx.x;
    const int w = t >> 6, l = t & 63;
    const int lm = l & 15, lg = l >> 4;

    const int arow = t >> 3;
    const int ac8 = (t & 7) << 3;
    const int bk = (t >> 3) << 1;
    const int bn4 = (t & 7) << 2;

    u16x8 pa[4][2];
    f32x4 pb[4][2];
    f32x4 acc[2] = {};

    #define OP_LOAD(slot_, kt_)                                                \
    {                                                                          \
        const int kg = ks0 + (kt_) * 64;                                       \
        pa[slot_][0] = *(const u16x8*)&obf[(size_t)arow * 4096 + kg + ac8];    \
        pa[slot_][1] = *(const u16x8*)&obf[(size_t)(arow + 32) * 4096 + kg + ac8]; \
        pb[slot_][0] = *(const f32x4*)&Wo[(size_t)(kg + bk) * 4096 + col0 + bn4]; \
        pb[slot_][1] = *(const f32x4*)&Wo[(size_t)(kg + bk + 1) * 4096 + col0 + bn4]; \
    }
    #define OP_STORE(buf_, slot_)                                              \
    {                                                                          \
        *(u16x8*)&As[buf_][arow][ac8] = pa[slot_][0];                          \
        *(u16x8*)&As[buf_][arow + 32][ac8] = pa[slot_][1];                     \
        _Pragma("unroll")                                                      \
        for (int j = 0; j < 4; j++) {                                          \
            int n = bn4 + j;                                                   \
            int idx = n * 64 + (bk ^ (((n >> 1) & 7) << 3));                   \
            ushort2 v2; v2.x = f2bf(pb[slot_][0][j]); v2.y = f2bf(pb[slot_][1][j]); \
            *(ushort2*)&Bs[buf_][idx] = v2;                                    \
        }                                                                      \
    }

    OP_LOAD(0, 0);
    OP_LOAD(1, 1);
    OP_LOAD(2, 2);
    OP_LOAD(3, 3);
    OP_STORE(0, 0);
    __syncthreads();

    #pragma unroll
    for (int kt = 0; kt < NKT; kt++) {
        const int cur = kt & 1;
        if (kt + 4 < NKT) OP_LOAD(kt & 3, kt + 4);
        if (kt + 1 < NKT) OP_STORE(cur ^ 1, (kt + 1) & 3);
        #pragma unroll
        for (int ks = 0; ks < 2; ks++) {
            const int koff = ks * 32 + lg * 8;
            bf16x8 a0 = *(const bf16x8*)&As[cur][w * 16 + lm][koff];
            #pragma unroll
            for (int nt = 0; nt < 2; nt++) {
                int n = nt * 16 + lm;
                bf16x8 b = *(const bf16x8*)
                    &Bs[cur][n * 64 + (koff ^ (((n >> 1) & 7) << 3))];
                acc[nt] = mfma16(a0, b, acc[nt]);
            }
        }
        if (kt + 1 < NKT) __syncthreads();
    }
    #pragma unroll
    for (int nt = 0; nt < 2; nt++)
        #pragma unroll
        for (int r = 0; r < 4; r++)
            parto[((size_t)osp * 64 + w * 16 + lg * 4 + r) * 4096 +
                  col0 + nt * 16 + lm] = acc[nt][r];
    #undef OP_LOAD
    #undef OP_STORE
}

// ------------------- Kernel 6: sum O-proj split-K partials ------------------
__global__ __launch_bounds__(256)
void k_osum(const float* __restrict__ parto, float* __restrict__ out0)
{
    int idx = blockIdx.x * 256 + threadIdx.x;
    float s = 0.f;
    #pragma unroll
    for (int o = 0; o < OSPLIT; o++)
        s += parto[(size_t)o * 262144 + idx];
    out0[idx] = s;
}

// ===================== DIAGNOSTIC PROBES (write to dead scratch) ============
// Probe A: fully contiguous grid-stride stream of Wq+Wk+Wv+Wo (164 MB).
__global__ __launch_bounds__(256)
void k_probeA(const float* __restrict__ wq, const float* __restrict__ wk,
              const float* __restrict__ wv, const float* __restrict__ wo,
              float* __restrict__ sink)
{
    const int tid = blockIdx.x * 256 + threadIdx.x;   // 2048 x 256
    const int stride = 2048 * 256;
    f32x4 s = {};
    {   const f32x4* p = (const f32x4*)wq;            // 16.78M f32
        #pragma unroll 4
        for (size_t j = tid; j < 4194304; j += stride) s += p[j]; }
    {   const f32x4* p = (const f32x4*)wk;
        #pragma unroll 4
        for (size_t j = tid; j < 1048576; j += stride) s += p[j]; }
    {   const f32x4* p = (const f32x4*)wv;
        #pragma unroll 4
        for (size_t j = tid; j < 1048576; j += stride) s += p[j]; }
    {   const f32x4* p = (const f32x4*)wo;
        #pragma unroll 4
        for (size_t j = tid; j < 4194304; j += stride) s += p[j]; }
    sink[tid] = s[0] + s[1] + s[2] + s[3];
}

// Probe C: k_qkv's EXACT W access pattern (grid (192,4), 32-col x 1024-k
// slices, 128 B per row per block), no LDS / MFMA / barriers. 100.7 MB.
__global__ __launch_bounds__(256)
void k_probeC(const float* __restrict__ Wq, const float* __restrict__ Wk,
              const float* __restrict__ Wv, float* __restrict__ sink)
{
    const int col0 = blockIdx.x * 32;
    const int ks0 = blockIdx.y * 1024;
    const float* W; int ldw, cbase;
    if (col0 < 4096)      { W = Wq; ldw = 4096; cbase = col0;        }
    else if (col0 < 5120) { W = Wk; ldw = 1024; cbase = col0 - 4096; }
    else                  { W = Wv; ldw = 1024; cbase = col0 - 5120; }
    const int t = threadIdx.x;
    const int bk = (t >> 3) << 1;
    const int bn4 = (t & 7) << 2;
    f32x4 s = {};
    #pragma unroll
    for (int kt = 0; kt < 16; kt++) {
        const int kg = ks0 + kt * 64;
        s += *(const f32x4*)&W[(size_t)(kg + bk) * ldw + cbase + bn4];
        s += *(const f32x4*)&W[(size_t)(kg + bk + 1) * ldw + cbase + bn4];
    }
    sink[(blockIdx.y * 192 + blockIdx.x) * 256 + t] = s[0] + s[1] + s[2] + s[3];
}

extern "C" void kernel_launch(void* const* d_in, const int* in_sizes, int n_in,
                              void* d_out, int out_size, void* d_ws, size_t ws_size,
                              hipStream_t stream)
{
    (void)in_sizes; (void)n_in; (void)out_size; (void)ws_size;
    const float* x      = (const float*)d_in[0];
    const float* xctx   = (const float*)d_in[1];
    const float* cosq   = (const float*)d_in[2];
    const float* sinq   = (const float*)d_in[3];
    const float* cosk   = (const float*)d_in[4];
    const float* sink_  = (const float*)d_in[5];
    const float* cacheK = (const float*)d_in[6];
    const float* cacheV = (const float*)d_in[7];
    const float* Wq     = (const float*)d_in[9];
    const float* Wk     = (const float*)d_in[10];
    const float* Wv     = (const float*)d_in[11];
    const float* Wo     = (const float*)d_in[12];
    const float* qnw    = (const float*)d_in[13];
    const float* knw    = (const float*)d_in[14];

    float* out0 = (float*)d_out;               // o@Wo (64, 4096)
    float* out1 = out0 + 262144;               // k (8, 128, 128)
    float* out2 = out1 + 131072;               // v (8, 128, 128)

    // Layout — total 26,738,688 B (extent proven writable in R7-R14).
    char* ws = (char*)d_ws;
    float* part  = (float*)(ws + 0);           // 4 x 128 x 6144 f32 = 12.6 MB
    u16*   kc    = (u16*)(ws + 0);
    u16*   vt    = (u16*)(ws + 8650752);
    u16*   opart = (u16*)(ws + 17301504);
    float* lpart = (float*)(ws + 23068672);
    float* parto = (float*)(ws + 0);
    u16*   fragA = (u16*)(ws + 25165824);
    u16*   qb    = (u16*)(ws + 25165824);
    u16*   kb    = (u16*)(ws + 25165824 + 524288);
    u16*   vb    = (u16*)(ws + 25165824 + 786432);
    u16*   obf   = (u16*)(ws + 25165824 + 1048576);
    // Probe sinks live in region A, which is re-produced by earlier kernels
    // on every call before any consumer reads it — replay-safe.
    float* sinkA = (float*)(ws + 0);           // 2 MB
    float* sinkC = (float*)(ws + 4194304);     // 0.75 MB

    k_prep<<<256, 256, 0, stream>>>(x, xctx, fragA);
    k_qkv<KSPLIT><<<dim3(192, KSPLIT), 256, 0, stream>>>(fragA, Wq, Wk, Wv, part);
    k_normrope<KSPLIT><<<1024, 256, 0, stream>>>(part, cosq, sinq, cosk, sink_,
                                                 qnw, knw, qb, kb, out1, out2, vb);
    k_prepkv<<<2640, 256, 0, stream>>>(cacheK, cacheV, kb, vb, kc, vt);
    k_attn<<<dim3(NSPLIT, 8, 2), 256, 0, stream>>>(qb, kc, vt, opart, lpart);
    k_combine<NSPLIT><<<128, 256, 0, stream>>>(opart, lpart, obf);
    k_oproj<<<dim3(128, OSPLIT), 256, 0, stream>>>(obf, Wo, parto);
    k_osum<<<1024, 256, 0, stream>>>(parto, out0);
    // Diagnostics (after outputs are final; sinks overwritten next call)
    k_probeA<<<2048, 256, 0, stream>>>(Wq, Wk, Wv, Wo, sinkA);
    k_probeC<<<dim3(192, 4), 256, 0, stream>>>(Wq, Wk, Wv, sinkC);
}

// Round 16
// 84.820 us; speedup vs baseline: 1.4170x; 1.4170x over previous
//
#include <hip/hip_runtime.h>

typedef unsigned short u16;
typedef __bf16 bf16x8 __attribute__((ext_vector_type(8)));
typedef float f32x4 __attribute__((ext_vector_type(4)));
typedef u16 u16x8 __attribute__((ext_vector_type(8)));

#define NSPLIT 11            // attention: 4224 keys = 11 splits * 6 * 64
#define ANBLK 6
#define KSPLIT 4             // qkv GEMM K-splits
#define OSPLIT 8             // oproj K-splits
#define SCALE_Q 0.08838834764831843f   // 1/sqrt(128), folded into q

__device__ __forceinline__ u16 f2bf(float f) {
    unsigned u = __builtin_bit_cast(unsigned, f);
    u += 0x7fff + ((u >> 16) & 1);     // RNE
    return (u16)(u >> 16);
}
__device__ __forceinline__ float bf2f(u16 h) {
    unsigned u = ((unsigned)h) << 16;
    return __builtin_bit_cast(float, u);
}
__device__ __forceinline__ f32x4 mfma16(bf16x8 a, bf16x8 b, f32x4 c) {
    return __builtin_amdgcn_mfma_f32_16x16x32_bf16(a, b, c, 0, 0, 0);
}

// ------ Kernel 0: pre-pack c=[x_ctx;x] as bf16 MFMA A-fragments (1 MB) ------
__global__ __launch_bounds__(256)
void k_prep(const float* __restrict__ x, const float* __restrict__ xctx,
            u16* __restrict__ fragA)
{
    int tid = blockIdx.x * 256 + threadIdx.x;   // 65536 threads
    int row = tid >> 9;
    int k0 = (tid & 511) << 3;
    const float* src = (row < 64) ? (xctx + (size_t)row * 4096)
                                  : (x + (size_t)(row - 64) * 4096);
    f32x4 v0 = *(const f32x4*)&src[k0];
    f32x4 v1 = *(const f32x4*)&src[k0 + 4];
    u16x8 o;
    o[0] = f2bf(v0[0]); o[1] = f2bf(v0[1]); o[2] = f2bf(v0[2]); o[3] = f2bf(v0[3]);
    o[4] = f2bf(v1[0]); o[5] = f2bf(v1[1]); o[6] = f2bf(v1[2]); o[7] = f2bf(v1[3]);
    int ks32 = k0 >> 5;
    int lg = (k0 >> 3) & 3;
    int rt = row >> 4;
    int l = lg * 16 + (row & 15);
    *(u16x8*)&fragA[(((size_t)ks32 * 8 + rt) * 64 + l) * 8] = o;
}

// --- Kernel 1: QKV projection — register-direct, NO LDS, NO barriers --------
// Structurally identical to probe C (proven ~6 TB/s): each lane loads its own
// B-fragment elements (8 ldw-strided scalars per fragment), double register
// buffer wv[2][32], consumers are cvt+MFMA only. A from pre-packed fragA.
template<int KS>
__global__ __launch_bounds__(256, 2)
void k_qkv(const u16* __restrict__ fragA,
           const float* __restrict__ Wq, const float* __restrict__ Wk,
           const float* __restrict__ Wv, float* __restrict__ part)
{
    constexpr int KCk = 4096 / KS;     // 1024
    constexpr int NKT = KCk / 64;      // 16
    const int col0 = blockIdx.x * 32;
    const int ksp = blockIdx.y;
    const int ks0 = ksp * KCk;
    const float* W; int ldw, cbase, mat;
    if (col0 < 4096)      { W = Wq; ldw = 4096; cbase = col0;        mat = 0; }
    else if (col0 < 5120) { W = Wk; ldw = 1024; cbase = col0 - 4096; mat = 1; }
    else                  { W = Wv; ldw = 1024; cbase = col0 - 5120; mat = 2; }
    const bool full = (mat != 0);          // k/v: 128 rows; q: 64 rows
    const int rowbase = full ? 0 : 64;

    const int t = threadIdx.x;
    const int w = t >> 6, l = t & 63;
    const int lm = l & 15, lg = l >> 4;
    const int rt0 = full ? (w * 2) : (4 + w);
    const int cA = cbase + lm;             // fragment col, nt=0
    const int cB = cbase + 16 + lm;        // fragment col, nt=1

    float wv[2][32];                       // [buf][ks2*16 + nt*8 + e]
    f32x4 acc[2][2] = {};

    #define WLOAD(pp_, kt_)                                                    \
    {                                                                          \
        const int kg = ks0 + (kt_) * 64 + lg * 8;                              \
        _Pragma("unroll")                                                      \
        for (int ks2 = 0; ks2 < 2; ks2++)                                      \
            _Pragma("unroll")                                                  \
            for (int e = 0; e < 8; e++) {                                      \
                wv[pp_][ks2 * 16 + e]     = W[(size_t)(kg + ks2 * 32 + e) * ldw + cA]; \
                wv[pp_][ks2 * 16 + 8 + e] = W[(size_t)(kg + ks2 * 32 + e) * ldw + cB]; \
            }                                                                  \
    }

    WLOAD(0, 0);
    #pragma unroll
    for (int kt = 0; kt < NKT; kt++) {
        const int pp = kt & 1;
        if (kt + 1 < NKT) WLOAD(pp ^ 1, kt + 1);
        const int kb32 = (ks0 >> 5) + kt * 2;
        #pragma unroll
        for (int ks2 = 0; ks2 < 2; ks2++) {
            bf16x8 b0, b1;
            #pragma unroll
            for (int e = 0; e < 8; e++) {
                b0[e] = (__bf16)wv[pp][ks2 * 16 + e];
                b1[e] = (__bf16)wv[pp][ks2 * 16 + 8 + e];
            }
            bf16x8 a0 = *(const bf16x8*)
                &fragA[(((size_t)(kb32 + ks2) * 8 + rt0) * 64 + l) * 8];
            acc[0][0] = mfma16(a0, b0, acc[0][0]);
            acc[0][1] = mfma16(a0, b1, acc[0][1]);
            if (full) {
                bf16x8 a1 = *(const bf16x8*)
                    &fragA[(((size_t)(kb32 + ks2) * 8 + rt0 + 1) * 64 + l) * 8];
                acc[1][0] = mfma16(a1, b0, acc[1][0]);
                acc[1][1] = mfma16(a1, b1, acc[1][1]);
            }
        }
    }

    const int wrows = full ? 32 : 16;
    const int mts = full ? 2 : 1;
    #pragma unroll
    for (int mt = 0; mt < 2; mt++) {
        if (mt >= mts) break;
        #pragma unroll
        for (int nt = 0; nt < 2; nt++)
            #pragma unroll
            for (int r = 0; r < 4; r++) {
                int grow = rowbase + w * wrows + mt * 16 + lg * 4 + r;
                part[((size_t)ksp * 128 + grow) * 6144 + col0 + nt * 16 + lm] =
                    acc[mt][nt][r];
            }
    }
    #undef WLOAD
}

// ------- Kernel 2: partial-sum + RMSNorm + RoPE (q, k) + v passthrough ------
template<int KS>
__global__ __launch_bounds__(256)
void k_normrope(const float* __restrict__ part,
                const float* __restrict__ cosq, const float* __restrict__ sinq,
                const float* __restrict__ cosk, const float* __restrict__ sink,
                const float* __restrict__ qnw, const float* __restrict__ knw,
                u16* __restrict__ qb, u16* __restrict__ kb,
                float* __restrict__ outk, float* __restrict__ outv,
                u16* __restrict__ vbw)
{
    int wid = blockIdx.x * 4 + (threadIdx.x >> 6);
    int lane = threadIdx.x & 63;
    if (wid < 2048) {                          // q: (h, l)
        int h = wid >> 6, lq = wid & 63;
        size_t ro = (size_t)(64 + lq) * 6144 + h * 128;
        float x1 = 0.f, x2 = 0.f;
        #pragma unroll
        for (int s = 0; s < KS; s++) {
            x1 += part[(size_t)s * 786432 + ro + lane];
            x2 += part[(size_t)s * 786432 + ro + lane + 64];
        }
        float ss = x1 * x1 + x2 * x2;
        #pragma unroll
        for (int off = 32; off; off >>= 1) ss += __shfl_xor(ss, off);
        float rms = rsqrtf(ss * (1.0f / 128.0f) + 1e-6f);
        float a = x1 * rms * qnw[lane];
        float b = x2 * rms * qnw[lane + 64];
        float c = cosq[lq * 64 + lane], s = sinq[lq * 64 + lane];
        u16* qo = qb + ((size_t)h * 64 + lq) * 128;
        qo[lane]      = f2bf((a * c - b * s) * SCALE_Q);
        qo[lane + 64] = f2bf((b * c + a * s) * SCALE_Q);
    } else if (wid < 3072) {                   // k: (kh, t)
        int rr = wid - 2048;
        int kh = rr >> 7, tt = rr & 127;
        size_t ro = (size_t)tt * 6144 + 4096 + kh * 128;
        float x1 = 0.f, x2 = 0.f;
        #pragma unroll
        for (int s = 0; s < KS; s++) {
            x1 += part[(size_t)s * 786432 + ro + lane];
            x2 += part[(size_t)s * 786432 + ro + lane + 64];
        }
        float ss = x1 * x1 + x2 * x2;
        #pragma unroll
        for (int off = 32; off; off >>= 1) ss += __shfl_xor(ss, off);
        float rms = rsqrtf(ss * (1.0f / 128.0f) + 1e-6f);
        float a = x1 * rms * knw[lane];
        float b = x2 * rms * knw[lane + 64];
        float c = cosk[tt * 64 + lane], s = sink[tt * 64 + lane];
        float o1 = a * c - b * s, o2 = b * c + a * s;
        size_t oi = ((size_t)kh * 128 + tt) * 128;
        outk[oi + lane] = o1; outk[oi + lane + 64] = o2;   // output 1 (k), f32
        kb[oi + lane] = f2bf(o1); kb[oi + lane + 64] = f2bf(o2);
    } else {                                   // v: (kh, t) partial sum only
        int rr = wid - 3072;
        int kh = rr >> 7, tt = rr & 127;
        size_t ro = (size_t)tt * 6144 + 5120 + kh * 128;
        float v1 = 0.f, v2 = 0.f;
        #pragma unroll
        for (int s = 0; s < KS; s++) {
            v1 += part[(size_t)s * 786432 + ro + lane];
            v2 += part[(size_t)s * 786432 + ro + lane + 64];
        }
        size_t oi = ((size_t)kh * 128 + tt) * 128;
        outv[oi + lane] = v1; outv[oi + lane + 64] = v2;   // output 2 (v), f32
        vbw[oi + lane] = f2bf(v1); vbw[oi + lane + 64] = f2bf(v2);
    }
}

// ------ Kernel 2.5: build bf16 kcache[kh][4224][128] + vcacheT[kh][128][4224]
__global__ __launch_bounds__(256)
void k_prepkv(const float* __restrict__ cacheK, const float* __restrict__ cacheV,
              const u16* __restrict__ kb, const u16* __restrict__ vb,
              u16* __restrict__ kc, u16* __restrict__ vt)
{
    const int bx = blockIdx.x;
    const int t = threadIdx.x;
    if (bx < 528) {                            // V^T tiles
        __shared__ __align__(16) u16 Ls[64][132];
        int kh = bx / 66, tile = bx % 66;
        int key0 = tile * 64;
        #pragma unroll
        for (int it = 0; it < 8; it++) {
            int fidx = it * 256 + t;
            int row = fidx >> 5;
            int d4 = (fidx & 31) << 2;
            int key = key0 + row;
            ushort4 sv;
            if (key < 4096) {
                float4 v = *(const float4*)&cacheV[((size_t)kh * 8192 + key) * 128 + d4];
                sv.x = f2bf(v.x); sv.y = f2bf(v.y); sv.z = f2bf(v.z); sv.w = f2bf(v.w);
            } else {
                sv = *(const ushort4*)&vb[((size_t)kh * 128 + (key - 4096)) * 128 + d4];
            }
            *(ushort4*)&Ls[row][d4] = sv;
        }
        __syncthreads();
        #pragma unroll
        for (int it = 0; it < 4; it++) {
            int fidx = it * 256 + t;
            int d = fidx >> 3;
            int kc8 = (fidx & 7) << 3;
            u16x8 o;
            #pragma unroll
            for (int j = 0; j < 8; j++) o[j] = Ls[kc8 + j][d];
            *(u16x8*)&vt[((size_t)kh * 128 + d) * 4224 + key0 + kc8] = o;
        }
    } else {                                   // K copy/convert
        size_t cidx = (size_t)(bx - 528) * 256 + t;
        int kh = (int)(cidx / 67584);
        int rem = (int)(cidx % 67584);
        int tt = rem >> 4;
        int d8 = (rem & 15) << 3;
        u16x8 o;
        if (tt < 4096) {
            const float* src = &cacheK[((size_t)kh * 8192 + tt) * 128 + d8];
            f32x4 a = *(const f32x4*)src;
            f32x4 b = *(const f32x4*)(src + 4);
            o[0] = f2bf(a[0]); o[1] = f2bf(a[1]); o[2] = f2bf(a[2]); o[3] = f2bf(a[3]);
            o[4] = f2bf(b[0]); o[5] = f2bf(b[1]); o[6] = f2bf(b[2]); o[7] = f2bf(b[3]);
        } else {
            o = *(const u16x8*)&kb[((size_t)kh * 128 + (tt - 4096)) * 128 + d8];
        }
        *(u16x8*)&kc[((size_t)kh * 4224 + tt) * 128 + d8] = o;
    }
}

// --------- Kernel 3: split-K flash attention (no-max online softmax) --------
__global__ __launch_bounds__(256)
void k_attn(const u16* __restrict__ qb, const u16* __restrict__ kcache,
            const u16* __restrict__ vcacheT,
            u16* __restrict__ opart, float* __restrict__ lpart)
{
    const int split = blockIdx.x;
    const int kh = blockIdx.y;
    const int z = blockIdx.z;
    const int t = threadIdx.x;
    const int w = t >> 6, l = t & 63;
    const int lm = l & 15, lg = l >> 4;
    const int rep = z * 2 + (w >> 1);
    const int mh = w & 1;

    __shared__ __align__(16) u16 Ks[64][136];
    __shared__ __align__(16) u16 Vs[128][72];
    __shared__ __align__(16) u16 Ps[4][32][40];

    const u16* qh = qb + ((size_t)(kh * 4 + rep) * 64) * 128;
    bf16x8 aq[2][4];
    #pragma unroll
    for (int mt = 0; mt < 2; mt++)
        #pragma unroll
        for (int ks = 0; ks < 4; ks++)
            aq[mt][ks] = *(const bf16x8*)
                &qh[(size_t)(mh * 32 + mt * 16 + lm) * 128 + ks * 32 + lg * 8];

    const u16* kcb = kcache + (size_t)kh * 4224 * 128;
    const u16* vtb = vcacheT + (size_t)kh * 128 * 4224;

    const int krow = t >> 4;
    const int kdc = (t & 15) << 3;
    const int vd = t >> 3;
    const int vkc = t & 7;

    u16x8 pk[4], pv[4];
    f32x4 accO[2][8] = {};
    float lacc[2][4] = {};

    #define AT_LOAD(key0_)                                                     \
    {                                                                          \
        _Pragma("unroll")                                                      \
        for (int it = 0; it < 4; it++)                                         \
            pk[it] = *(const u16x8*)&kcb[(size_t)((key0_) + it * 16 + krow) * 128 + kdc]; \
        _Pragma("unroll")                                                      \
        for (int it = 0; it < 4; it++)                                         \
            pv[it] = *(const u16x8*)&vtb[(size_t)(it * 32 + vd) * 4224 + (key0_) + vkc * 8]; \
    }
    #define AT_STORE()                                                         \
    {                                                                          \
        _Pragma("unroll")                                                      \
        for (int it = 0; it < 4; it++)                                         \
            *(u16x8*)&Ks[it * 16 + krow][kdc] = pk[it];                        \
        _Pragma("unroll")                                                      \
        for (int it = 0; it < 4; it++) {                                       \
            int d = it * 32 + vd;                                              \
            *(u16x8*)&Vs[d][(vkc ^ ((d >> 2) & 7)) << 3] = pv[it];             \
        }                                                                      \
    }

    AT_LOAD(split * (64 * ANBLK));
    #pragma unroll 1
    for (int kbi = 0; kbi < ANBLK; kbi++) {
        __syncthreads();
        AT_STORE();
        __syncthreads();
        if (kbi + 1 < ANBLK) AT_LOAD(split * (64 * ANBLK) + (kbi + 1) * 64);

        f32x4 sa[2][4] = {};
        #pragma unroll
        for (int ks = 0; ks < 4; ks++) {
            bf16x8 bk[4];
            #pragma unroll
            for (int nt = 0; nt < 4; nt++)
                bk[nt] = *(const bf16x8*)&Ks[nt * 16 + lm][ks * 32 + lg * 8];
            #pragma unroll
            for (int mt = 0; mt < 2; mt++)
                #pragma unroll
                for (int nt = 0; nt < 4; nt++)
                    sa[mt][nt] = mfma16(aq[mt][ks], bk[nt], sa[mt][nt]);
        }

        #pragma unroll
        for (int half = 0; half < 2; half++) {
            #pragma unroll
            for (int mt = 0; mt < 2; mt++)
                #pragma unroll
                for (int nt2 = 0; nt2 < 2; nt2++)
                    #pragma unroll
                    for (int r = 0; r < 4; r++) {
                        float e = __expf(sa[mt][half * 2 + nt2][r]);
                        lacc[mt][r] += e;
                        Ps[w][mt * 16 + lg * 4 + r][nt2 * 16 + lm] = f2bf(e);
                    }
            bf16x8 pa[2];
            #pragma unroll
            for (int mt = 0; mt < 2; mt++)
                pa[mt] = *(const bf16x8*)&Ps[w][mt * 16 + lm][lg * 8];
            #pragma unroll
            for (int dt = 0; dt < 8; dt++) {
                int d = dt * 16 + lm;
                int vswz = ((d >> 2) & 7) << 3;
                bf16x8 vb8 = *(const bf16x8*)&Vs[d][(half * 32 + lg * 8) ^ vswz];
                #pragma unroll
                for (int mt = 0; mt < 2; mt++)
                    accO[mt][dt] = mfma16(pa[mt], vb8, accO[mt][dt]);
            }
        }
    }
    #undef AT_LOAD
    #undef AT_STORE

    #pragma unroll
    for (int mt = 0; mt < 2; mt++)
        #pragma unroll
        for (int r = 0; r < 4; r++) {
            float v = lacc[mt][r];
            v += __shfl_xor(v, 1);
            v += __shfl_xor(v, 2);
            v += __shfl_xor(v, 4);
            v += __shfl_xor(v, 8);
            lacc[mt][r] = v;
        }

    const size_t base = (((size_t)kh * NSPLIT + split) * 4 + rep) * 64 + mh * 32;
    if (lm == 0) {
        #pragma unroll
        for (int mt = 0; mt < 2; mt++)
            #pragma unroll
            for (int r = 0; r < 4; r++)
                lpart[base + mt * 16 + lg * 4 + r] = lacc[mt][r];
    }
    #pragma unroll
    for (int mt = 0; mt < 2; mt++)
        #pragma unroll
        for (int dt = 0; dt < 8; dt++)
            #pragma unroll
            for (int r = 0; r < 4; r++)
                opart[(base + mt * 16 + lg * 4 + r) * 128 + dt * 16 + lm] =
                    f2bf(accO[mt][dt][r]);
}

// ---------- Kernel 4: combine splits, normalize (vectorized u16x8) ----------
template<int NSP>
__global__ __launch_bounds__(256)
void k_combine(const u16* __restrict__ opart, const float* __restrict__ lpart,
               u16* __restrict__ obf)
{
    int idx = blockIdx.x * 256 + threadIdx.x;
    int lq = idx >> 9;
    int c8 = (idx & 511) << 3;
    int h = c8 >> 7, d = c8 & 127;
    int kh = h >> 2, rep = h & 3;
    float os[8] = {};
    float ls = 0.f;
    #pragma unroll
    for (int s = 0; s < NSP; s++) {
        size_t b = (((size_t)kh * NSP + s) * 4 + rep) * 64 + lq;
        u16x8 v = *(const u16x8*)&opart[b * 128 + d];
        #pragma unroll
        for (int j = 0; j < 8; j++) os[j] += bf2f(v[j]);
        ls += lpart[b];
    }
    float inv = 1.0f / ls;
    u16x8 o;
    #pragma unroll
    for (int j = 0; j < 8; j++) o[j] = f2bf(os[j] * inv);
    *(u16x8*)&obf[(size_t)lq * 4096 + c8] = o;
}

// ------ Kernel 5: O projection, split-K, 4-deep register-ring (R11) ---------
__global__ __launch_bounds__(256)
void k_oproj(const u16* __restrict__ obf, const float* __restrict__ Wo,
             float* __restrict__ parto)
{
    constexpr int NKT = 4096 / OSPLIT / 64;    // 8
    const int col0 = blockIdx.x * 32;
    const int osp = blockIdx.y;
    const int ks0 = osp * (4096 / OSPLIT);

    __shared__ __align__(16) u16 As[2][64][72];
    __shared__ __align__(16) u16 Bs[2][32 * 64];

    const int t = threadIdx.x;
    const int w = t >> 6, l = t & 63;
    const int lm = l & 15, lg = l >> 4;

    const int arow = t >> 3;
    const int ac8 = (t & 7) << 3;
    const int bk = (t >> 3) << 1;
    const int bn4 = (t & 7) << 2;

    u16x8 pa[4][2];
    f32x4 pb[4][2];
    f32x4 acc[2] = {};

    #define OP_LOAD(slot_, kt_)                                                \
    {                                                                          \
        const int kg = ks0 + (kt_) * 64;                                       \
        pa[slot_][0] = *(const u16x8*)&obf[(size_t)arow * 4096 + kg + ac8];    \
        pa[slot_][1] = *(const u16x8*)&obf[(size_t)(arow + 32) * 4096 + kg + ac8]; \
        pb[slot_][0] = *(const f32x4*)&Wo[(size_t)(kg + bk) * 4096 + col0 + bn4]; \
        pb[slot_][1] = *(const f32x4*)&Wo[(size_t)(kg + bk + 1) * 4096 + col0 + bn4]; \
    }
    #define OP_STORE(buf_, slot_)                                              \
    {                                                                          \
        *(u16x8*)&As[buf_][arow][ac8] = pa[slot_][0];                          \
        *(u16x8*)&As[buf_][arow + 32][ac8] = pa[slot_][1];                     \
        _Pragma("unroll")                                                      \
        for (int j = 0; j < 4; j++) {                                          \
            int n = bn4 + j;                                                   \
            int idx = n * 64 + (bk ^ (((n >> 1) & 7) << 3));                   \
            ushort2 v2; v2.x = f2bf(pb[slot_][0][j]); v2.y = f2bf(pb[slot_][1][j]); \
            *(ushort2*)&Bs[buf_][idx] = v2;                                    \
        }                                                                      \
    }

    OP_LOAD(0, 0);
    OP_LOAD(1, 1);
    OP_LOAD(2, 2);
    OP_LOAD(3, 3);
    OP_STORE(0, 0);
    __syncthreads();

    #pragma unroll
    for (int kt = 0; kt < NKT; kt++) {
        const int cur = kt & 1;
        if (kt + 4 < NKT) OP_LOAD(kt & 3, kt + 4);
        if (kt + 1 < NKT) OP_STORE(cur ^ 1, (kt + 1) & 3);
        #pragma unroll
        for (int ks = 0; ks < 2; ks++) {
            const int koff = ks * 32 + lg * 8;
            bf16x8 a0 = *(const bf16x8*)&As[cur][w * 16 + lm][koff];
            #pragma unroll
            for (int nt = 0; nt < 2; nt++) {
                int n = nt * 16 + lm;
                bf16x8 b = *(const bf16x8*)
                    &Bs[cur][n * 64 + (koff ^ (((n >> 1) & 7) << 3))];
                acc[nt] = mfma16(a0, b, acc[nt]);
            }
        }
        if (kt + 1 < NKT) __syncthreads();
    }
    #pragma unroll
    for (int nt = 0; nt < 2; nt++)
        #pragma unroll
        for (int r = 0; r < 4; r++)
            parto[((size_t)osp * 64 + w * 16 + lg * 4 + r) * 4096 +
                  col0 + nt * 16 + lm] = acc[nt][r];
    #undef OP_LOAD
    #undef OP_STORE
}

// ------------------- Kernel 6: sum O-proj split-K partials ------------------
__global__ __launch_bounds__(256)
void k_osum(const float* __restrict__ parto, float* __restrict__ out0)
{
    int idx = blockIdx.x * 256 + threadIdx.x;
    float s = 0.f;
    #pragma unroll
    for (int o = 0; o < OSPLIT; o++)
        s += parto[(size_t)o * 262144 + idx];
    out0[idx] = s;
}

extern "C" void kernel_launch(void* const* d_in, const int* in_sizes, int n_in,
                              void* d_out, int out_size, void* d_ws, size_t ws_size,
                              hipStream_t stream)
{
    (void)in_sizes; (void)n_in; (void)out_size; (void)ws_size;
    const float* x      = (const float*)d_in[0];
    const float* xctx   = (const float*)d_in[1];
    const float* cosq   = (const float*)d_in[2];
    const float* sinq   = (const float*)d_in[3];
    const float* cosk   = (const float*)d_in[4];
    const float* sink_  = (const float*)d_in[5];
    const float* cacheK = (const float*)d_in[6];
    const float* cacheV = (const float*)d_in[7];
    const float* Wq     = (const float*)d_in[9];
    const float* Wk     = (const float*)d_in[10];
    const float* Wv     = (const float*)d_in[11];
    const float* Wo     = (const float*)d_in[12];
    const float* qnw    = (const float*)d_in[13];
    const float* knw    = (const float*)d_in[14];

    float* out0 = (float*)d_out;               // o@Wo (64, 4096)
    float* out1 = out0 + 262144;               // k (8, 128, 128)
    float* out2 = out1 + 131072;               // v (8, 128, 128)

    // Layout — total 26,738,688 B (extent proven writable in R7-R15).
    char* ws = (char*)d_ws;
    float* part  = (float*)(ws + 0);           // 4 x 128 x 6144 f32 = 12.6 MB
    u16*   kc    = (u16*)(ws + 0);
    u16*   vt    = (u16*)(ws + 8650752);
    u16*   opart = (u16*)(ws + 17301504);
    float* lpart = (float*)(ws + 23068672);
    float* parto = (float*)(ws + 0);
    u16*   fragA = (u16*)(ws + 25165824);
    u16*   qb    = (u16*)(ws + 25165824);
    u16*   kb    = (u16*)(ws + 25165824 + 524288);
    u16*   vb    = (u16*)(ws + 25165824 + 786432);
    u16*   obf   = (u16*)(ws + 25165824 + 1048576);

    k_prep<<<256, 256, 0, stream>>>(x, xctx, fragA);
    k_qkv<KSPLIT><<<dim3(192, KSPLIT), 256, 0, stream>>>(fragA, Wq, Wk, Wv, part);
    k_normrope<KSPLIT><<<1024, 256, 0, stream>>>(part, cosq, sinq, cosk, sink_,
                                                 qnw, knw, qb, kb, out1, out2, vb);
    k_prepkv<<<2640, 256, 0, stream>>>(cacheK, cacheV, kb, vb, kc, vt);
    k_attn<<<dim3(NSPLIT, 8, 2), 256, 0, stream>>>(qb, kc, vt, opart, lpart);
    k_combine<NSPLIT><<<128, 256, 0, stream>>>(opart, lpart, obf);
    k_oproj<<<dim3(128, OSPLIT), 256, 0, stream>>>(obf, Wo, parto);
    k_osum<<<1024, 256, 0, stream>>>(parto, out0);
}

// Round 18
// 77.598 us; speedup vs baseline: 1.5489x; 1.0931x over previous
//
#include <hip/hip_runtime.h>

typedef unsigned short u16;
typedef __bf16 bf16x8 __attribute__((ext_vector_type(8)));
typedef float f32x4 __attribute__((ext_vector_type(4)));
typedef u16 u16x8 __attribute__((ext_vector_type(8)));

#define NSPLIT 11            // attention: 4224 keys = 11 splits * 6 * 64
#define ANBLK 6
#define KSPLIT 4             // qkv GEMM K-splits
#define OSPLIT 8             // oproj K-splits
#define SCALE_Q 0.08838834764831843f   // 1/sqrt(128), folded into q

__device__ __forceinline__ u16 f2bf(float f) {
    unsigned u = __builtin_bit_cast(unsigned, f);
    u += 0x7fff + ((u >> 16) & 1);     // RNE
    return (u16)(u >> 16);
}
__device__ __forceinline__ float bf2f(u16 h) {
    unsigned u = ((unsigned)h) << 16;
    return __builtin_bit_cast(float, u);
}
__device__ __forceinline__ f32x4 mfma16(bf16x8 a, bf16x8 b, f32x4 c) {
    return __builtin_amdgcn_mfma_f32_16x16x32_bf16(a, b, c, 0, 0, 0);
}

// ------ Kernel 0: pre-pack c=[x_ctx;x] as bf16 MFMA A-fragments (1 MB) ------
__global__ __launch_bounds__(256)
void k_prep(const float* __restrict__ x, const float* __restrict__ xctx,
            u16* __restrict__ fragA)
{
    int tid = blockIdx.x * 256 + threadIdx.x;   // 65536 threads
    int row = tid >> 9;
    int k0 = (tid & 511) << 3;
    const float* src = (row < 64) ? (xctx + (size_t)row * 4096)
                                  : (x + (size_t)(row - 64) * 4096);
    f32x4 v0 = *(const f32x4*)&src[k0];
    f32x4 v1 = *(const f32x4*)&src[k0 + 4];
    u16x8 o;
    o[0] = f2bf(v0[0]); o[1] = f2bf(v0[1]); o[2] = f2bf(v0[2]); o[3] = f2bf(v0[3]);
    o[4] = f2bf(v1[0]); o[5] = f2bf(v1[1]); o[6] = f2bf(v1[2]); o[7] = f2bf(v1[3]);
    int ks32 = k0 >> 5;
    int lg = (k0 >> 3) & 3;
    int rt = row >> 4;
    int l = lg * 16 + (row & 15);
    *(u16x8*)&fragA[(((size_t)ks32 * 8 + rt) * 64 + l) * 8] = o;
}

// ------ Kernel 1: QKV projection, split-K, 4-deep register-ring pipeline ----
// grid (192, KS). W loads issued 4 steps ahead into pb[4][2]; fragA fragments
// 1 step ahead into af[2][4]. Fully unrolled so ring indices are static.
template<int KS>
__global__ __launch_bounds__(256)
void k_qkv(const u16* __restrict__ fragA,
           const float* __restrict__ Wq, const float* __restrict__ Wk,
           const float* __restrict__ Wv, float* __restrict__ part)
{
    constexpr int KCk = 4096 / KS;
    constexpr int NKT = KCk / 64;
    const int col0 = blockIdx.x * 32;
    const int ksp = blockIdx.y;
    const int ks0 = ksp * KCk;
    const float* W; int ldw, cbase, mat;
    if (col0 < 4096)      { W = Wq; ldw = 4096; cbase = col0;        mat = 0; }
    else if (col0 < 5120) { W = Wk; ldw = 1024; cbase = col0 - 4096; mat = 1; }
    else                  { W = Wv; ldw = 1024; cbase = col0 - 5120; mat = 2; }
    const bool full = (mat != 0);
    const int rowbase = full ? 0 : 64;

    __shared__ __align__(16) u16 Bs[2][32 * 64];   // double-buffered, 8KB

    const int t = threadIdx.x;
    const int w = t >> 6, l = t & 63;
    const int lm = l & 15, lg = l >> 4;
    const int bk = (t >> 3) << 1;
    const int bn4 = (t & 7) << 2;

    f32x4 pb[4][2];                    // W ring, 4 steps deep
    bf16x8 af[2][4];                   // fragA double buffer
    f32x4 acc[2][2] = {};
    const int rt0 = full ? (w * 2) : (4 + w);

    #define QKV_BLOAD(slot_, kt_)                                              \
    {                                                                          \
        const int kg = ks0 + (kt_) * 64;                                       \
        pb[slot_][0] = *(const f32x4*)&W[(size_t)(kg + bk) * ldw + cbase + bn4]; \
        pb[slot_][1] = *(const f32x4*)&W[(size_t)(kg + bk + 1) * ldw + cbase + bn4]; \
    }
    #define QKV_BSTORE(buf_, slot_)                                            \
    {                                                                          \
        _Pragma("unroll")                                                      \
        for (int j = 0; j < 4; j++) {                                          \
            int n = bn4 + j;                                                   \
            int idx = n * 64 + (bk ^ (((n >> 1) & 7) << 3));                   \
            ushort2 v2; v2.x = f2bf(pb[slot_][0][j]); v2.y = f2bf(pb[slot_][1][j]); \
            *(ushort2*)&Bs[buf_][idx] = v2;                                    \
        }                                                                      \
    }
    #define QKV_ALOAD(p_, kt_)                                                 \
    {                                                                          \
        const int kb32 = (ks0 >> 5) + (kt_) * 2;                               \
        af[p_][0] = *(const bf16x8*)&fragA[(((size_t)kb32 * 8 + rt0) * 64 + l) * 8]; \
        af[p_][1] = *(const bf16x8*)&fragA[(((size_t)(kb32 + 1) * 8 + rt0) * 64 + l) * 8]; \
        if (full) {                                                            \
            af[p_][2] = *(const bf16x8*)&fragA[(((size_t)kb32 * 8 + rt0 + 1) * 64 + l) * 8]; \
            af[p_][3] = *(const bf16x8*)&fragA[(((size_t)(kb32 + 1) * 8 + rt0 + 1) * 64 + l) * 8]; \
        }                                                                      \
    }

    QKV_BLOAD(0, 0);
    QKV_BLOAD(1, 1);
    QKV_BLOAD(2, 2);
    QKV_BLOAD(3, 3);
    QKV_ALOAD(0, 0);
    QKV_BSTORE(0, 0);
    __syncthreads();

    #pragma unroll
    for (int kt = 0; kt < NKT; kt++) {
        const int cur = kt & 1;
        if (kt + 4 < NKT) QKV_BLOAD(kt & 3, kt + 4);
        if (kt + 1 < NKT) QKV_ALOAD((kt + 1) & 1, kt + 1);
        if (kt + 1 < NKT) QKV_BSTORE(cur ^ 1, (kt + 1) & 3);
        #pragma unroll
        for (int ks = 0; ks < 2; ks++) {
            const int koff = ks * 32 + lg * 8;
            bf16x8 bfr[2];
            #pragma unroll
            for (int nt = 0; nt < 2; nt++) {
                int n = nt * 16 + lm;
                bfr[nt] = *(const bf16x8*)
                    &Bs[cur][n * 64 + (koff ^ (((n >> 1) & 7) << 3))];
            }
            acc[0][0] = mfma16(af[cur][ks], bfr[0], acc[0][0]);
            acc[0][1] = mfma16(af[cur][ks], bfr[1], acc[0][1]);
            if (full) {
                acc[1][0] = mfma16(af[cur][2 + ks], bfr[0], acc[1][0]);
                acc[1][1] = mfma16(af[cur][2 + ks], bfr[1], acc[1][1]);
            }
        }
        if (kt + 1 < NKT) __syncthreads();
    }

    const int wrows = full ? 32 : 16;
    const int mts = full ? 2 : 1;
    #pragma unroll
    for (int mt = 0; mt < 2; mt++) {
        if (mt >= mts) break;
        #pragma unroll
        for (int nt = 0; nt < 2; nt++)
            #pragma unroll
            for (int r = 0; r < 4; r++) {
                int grow = rowbase + w * wrows + mt * 16 + lg * 4 + r;
                part[((size_t)ksp * 128 + grow) * 6144 + col0 + nt * 16 + lm] =
                    acc[mt][nt][r];
            }
    }
    #undef QKV_BLOAD
    #undef QKV_BSTORE
    #undef QKV_ALOAD
}

// ------- Kernel 2: partial-sum + RMSNorm + RoPE (q, k) + v passthrough ------
template<int KS>
__global__ __launch_bounds__(256)
void k_normrope(const float* __restrict__ part,
                const float* __restrict__ cosq, const float* __restrict__ sinq,
                const float* __restrict__ cosk, const float* __restrict__ sink,
                const float* __restrict__ qnw, const float* __restrict__ knw,
                u16* __restrict__ qb, u16* __restrict__ kb,
                float* __restrict__ outk, float* __restrict__ outv,
                u16* __restrict__ vbw)
{
    int wid = blockIdx.x * 4 + (threadIdx.x >> 6);
    int lane = threadIdx.x & 63;
    if (wid < 2048) {                          // q: (h, l)
        int h = wid >> 6, lq = wid & 63;
        size_t ro = (size_t)(64 + lq) * 6144 + h * 128;
        float x1 = 0.f, x2 = 0.f;
        #pragma unroll
        for (int s = 0; s < KS; s++) {
            x1 += part[(size_t)s * 786432 + ro + lane];
            x2 += part[(size_t)s * 786432 + ro + lane + 64];
        }
        float ss = x1 * x1 + x2 * x2;
        #pragma unroll
        for (int off = 32; off; off >>= 1) ss += __shfl_xor(ss, off);
        float rms = rsqrtf(ss * (1.0f / 128.0f) + 1e-6f);
        float a = x1 * rms * qnw[lane];
        float b = x2 * rms * qnw[lane + 64];
        float c = cosq[lq * 64 + lane], s = sinq[lq * 64 + lane];
        u16* qo = qb + ((size_t)h * 64 + lq) * 128;
        qo[lane]      = f2bf((a * c - b * s) * SCALE_Q);
        qo[lane + 64] = f2bf((b * c + a * s) * SCALE_Q);
    } else if (wid < 3072) {                   // k: (kh, t)
        int rr = wid - 2048;
        int kh = rr >> 7, tt = rr & 127;
        size_t ro = (size_t)tt * 6144 + 4096 + kh * 128;
        float x1 = 0.f, x2 = 0.f;
        #pragma unroll
        for (int s = 0; s < KS; s++) {
            x1 += part[(size_t)s * 786432 + ro + lane];
            x2 += part[(size_t)s * 786432 + ro + lane + 64];
        }
        float ss = x1 * x1 + x2 * x2;
        #pragma unroll
        for (int off = 32; off; off >>= 1) ss += __shfl_xor(ss, off);
        float rms = rsqrtf(ss * (1.0f / 128.0f) + 1e-6f);
        float a = x1 * rms * knw[lane];
        float b = x2 * rms * knw[lane + 64];
        float c = cosk[tt * 64 + lane], s = sink[tt * 64 + lane];
        float o1 = a * c - b * s, o2 = b * c + a * s;
        size_t oi = ((size_t)kh * 128 + tt) * 128;
        outk[oi + lane] = o1; outk[oi + lane + 64] = o2;   // output 1 (k), f32
        kb[oi + lane] = f2bf(o1); kb[oi + lane + 64] = f2bf(o2);
    } else {                                   // v: (kh, t) partial sum only
        int rr = wid - 3072;
        int kh = rr >> 7, tt = rr & 127;
        size_t ro = (size_t)tt * 6144 + 5120 + kh * 128;
        float v1 = 0.f, v2 = 0.f;
        #pragma unroll
        for (int s = 0; s < KS; s++) {
            v1 += part[(size_t)s * 786432 + ro + lane];
            v2 += part[(size_t)s * 786432 + ro + lane + 64];
        }
        size_t oi = ((size_t)kh * 128 + tt) * 128;
        outv[oi + lane] = v1; outv[oi + lane + 64] = v2;   // output 2 (v), f32
        vbw[oi + lane] = f2bf(v1); vbw[oi + lane + 64] = f2bf(v2);
    }
}

// ------ Kernel 2.5: build bf16 kcache[kh][4224][128] + vcacheT[kh][128][4224]
__global__ __launch_bounds__(256)
void k_prepkv(const float* __restrict__ cacheK, const float* __restrict__ cacheV,
              const u16* __restrict__ kb, const u16* __restrict__ vb,
              u16* __restrict__ kc, u16* __restrict__ vt)
{
    const int bx = blockIdx.x;
    const int t = threadIdx.x;
    if (bx < 528) {                            // V^T tiles
        __shared__ __align__(16) u16 Ls[64][132];
        int kh = bx / 66, tile = bx % 66;
        int key0 = tile * 64;
        #pragma unroll
        for (int it = 0; it < 8; it++) {
            int fidx = it * 256 + t;
            int row = fidx >> 5;
            int d4 = (fidx & 31) << 2;
            int key = key0 + row;
            ushort4 sv;
            if (key < 4096) {
                float4 v = *(const float4*)&cacheV[((size_t)kh * 8192 + key) * 128 + d4];
                sv.x = f2bf(v.x); sv.y = f2bf(v.y); sv.z = f2bf(v.z); sv.w = f2bf(v.w);
            } else {
                sv = *(const ushort4*)&vb[((size_t)kh * 128 + (key - 4096)) * 128 + d4];
            }
            *(ushort4*)&Ls[row][d4] = sv;
        }
        __syncthreads();
        #pragma unroll
        for (int it = 0; it < 4; it++) {
            int fidx = it * 256 + t;
            int d = fidx >> 3;
            int kc8 = (fidx & 7) << 3;
            u16x8 o;
            #pragma unroll
            for (int j = 0; j < 8; j++) o[j] = Ls[kc8 + j][d];
            *(u16x8*)&vt[((size_t)kh * 128 + d) * 4224 + key0 + kc8] = o;
        }
    } else {                                   // K copy/convert
        size_t cidx = (size_t)(bx - 528) * 256 + t;
        int kh = (int)(cidx / 67584);
        int rem = (int)(cidx % 67584);
        int tt = rem >> 4;
        int d8 = (rem & 15) << 3;
        u16x8 o;
        if (tt < 4096) {
            const float* src = &cacheK[((size_t)kh * 8192 + tt) * 128 + d8];
            f32x4 a = *(const f32x4*)src;
            f32x4 b = *(const f32x4*)(src + 4);
            o[0] = f2bf(a[0]); o[1] = f2bf(a[1]); o[2] = f2bf(a[2]); o[3] = f2bf(a[3]);
            o[4] = f2bf(b[0]); o[5] = f2bf(b[1]); o[6] = f2bf(b[2]); o[7] = f2bf(b[3]);
        } else {
            o = *(const u16x8*)&kb[((size_t)kh * 128 + (tt - 4096)) * 128 + d8];
        }
        *(u16x8*)&kc[((size_t)kh * 4224 + tt) * 128 + d8] = o;
    }
}

// --------- Kernel 3: split-K flash attention (no-max online softmax) --------
__global__ __launch_bounds__(256)
void k_attn(const u16* __restrict__ qb, const u16* __restrict__ kcache,
            const u16* __restrict__ vcacheT,
            u16* __restrict__ opart, float* __restrict__ lpart)
{
    const int split = blockIdx.x;
    const int kh = blockIdx.y;
    const int z = blockIdx.z;
    const int t = threadIdx.x;
    const int w = t >> 6, l = t & 63;
    const int lm = l & 15, lg = l >> 4;
    const int rep = z * 2 + (w >> 1);
    const int mh = w & 1;

    __shared__ __align__(16) u16 Ks[64][136];
    __shared__ __align__(16) u16 Vs[128][72];
    __shared__ __align__(16) u16 Ps[4][32][40];

    const u16* qh = qb + ((size_t)(kh * 4 + rep) * 64) * 128;
    bf16x8 aq[2][4];
    #pragma unroll
    for (int mt = 0; mt < 2; mt++)
        #pragma unroll
        for (int ks = 0; ks < 4; ks++)
            aq[mt][ks] = *(const bf16x8*)
                &qh[(size_t)(mh * 32 + mt * 16 + lm) * 128 + ks * 32 + lg * 8];

    const u16* kcb = kcache + (size_t)kh * 4224 * 128;
    const u16* vtb = vcacheT + (size_t)kh * 128 * 4224;

    const int krow = t >> 4;
    const int kdc = (t & 15) << 3;
    const int vd = t >> 3;
    const int vkc = t & 7;

    u16x8 pk[4], pv[4];
    f32x4 accO[2][8] = {};
    float lacc[2][4] = {};

    #define AT_LOAD(key0_)                                                     \
    {                                                                          \
        _Pragma("unroll")                                                      \
        for (int it = 0; it < 4; it++)                                         \
            pk[it] = *(const u16x8*)&kcb[(size_t)((key0_) + it * 16 + krow) * 128 + kdc]; \
        _Pragma("unroll")                                                      \
        for (int it = 0; it < 4; it++)                                         \
            pv[it] = *(const u16x8*)&vtb[(size_t)(it * 32 + vd) * 4224 + (key0_) + vkc * 8]; \
    }
    #define AT_STORE()                                                         \
    {                                                                          \
        _Pragma("unroll")                                                      \
        for (int it = 0; it < 4; it++)                                         \
            *(u16x8*)&Ks[it * 16 + krow][kdc] = pk[it];                        \
        _Pragma("unroll")                                                      \
        for (int it = 0; it < 4; it++) {                                       \
            int d = it * 32 + vd;                                              \
            *(u16x8*)&Vs[d][(vkc ^ ((d >> 2) & 7)) << 3] = pv[it];             \
        }                                                                      \
    }

    AT_LOAD(split * (64 * ANBLK));
    #pragma unroll 1
    for (int kbi = 0; kbi < ANBLK; kbi++) {
        __syncthreads();
        AT_STORE();
        __syncthreads();
        if (kbi + 1 < ANBLK) AT_LOAD(split * (64 * ANBLK) + (kbi + 1) * 64);

        f32x4 sa[2][4] = {};
        #pragma unroll
        for (int ks = 0; ks < 4; ks++) {
            bf16x8 bk[4];
            #pragma unroll
            for (int nt = 0; nt < 4; nt++)
                bk[nt] = *(const bf16x8*)&Ks[nt * 16 + lm][ks * 32 + lg * 8];
            #pragma unroll
            for (int mt = 0; mt < 2; mt++)
                #pragma unroll
                for (int nt = 0; nt < 4; nt++)
                    sa[mt][nt] = mfma16(aq[mt][ks], bk[nt], sa[mt][nt]);
        }

        #pragma unroll
        for (int half = 0; half < 2; half++) {
            #pragma unroll
            for (int mt = 0; mt < 2; mt++)
                #pragma unroll
                for (int nt2 = 0; nt2 < 2; nt2++)
                    #pragma unroll
                    for (int r = 0; r < 4; r++) {
                        float e = __expf(sa[mt][half * 2 + nt2][r]);
                        lacc[mt][r] += e;
                        Ps[w][mt * 16 + lg * 4 + r][nt2 * 16 + lm] = f2bf(e);
                    }
            bf16x8 pa[2];
            #pragma unroll
            for (int mt = 0; mt < 2; mt++)
                pa[mt] = *(const bf16x8*)&Ps[w][mt * 16 + lm][lg * 8];
            #pragma unroll
            for (int dt = 0; dt < 8; dt++) {
                int d = dt * 16 + lm;
                int vswz = ((d >> 2) & 7) << 3;
                bf16x8 vb8 = *(const bf16x8*)&Vs[d][(half * 32 + lg * 8) ^ vswz];
                #pragma unroll
                for (int mt = 0; mt < 2; mt++)
                    accO[mt][dt] = mfma16(pa[mt], vb8, accO[mt][dt]);
            }
        }
    }
    #undef AT_LOAD
    #undef AT_STORE

    #pragma unroll
    for (int mt = 0; mt < 2; mt++)
        #pragma unroll
        for (int r = 0; r < 4; r++) {
            float v = lacc[mt][r];
            v += __shfl_xor(v, 1);
            v += __shfl_xor(v, 2);
            v += __shfl_xor(v, 4);
            v += __shfl_xor(v, 8);
            lacc[mt][r] = v;
        }

    const size_t base = (((size_t)kh * NSPLIT + split) * 4 + rep) * 64 + mh * 32;
    if (lm == 0) {
        #pragma unroll
        for (int mt = 0; mt < 2; mt++)
            #pragma unroll
            for (int r = 0; r < 4; r++)
                lpart[base + mt * 16 + lg * 4 + r] = lacc[mt][r];
    }
    #pragma unroll
    for (int mt = 0; mt < 2; mt++)
        #pragma unroll
        for (int dt = 0; dt < 8; dt++)
            #pragma unroll
            for (int r = 0; r < 4; r++)
                opart[(base + mt * 16 + lg * 4 + r) * 128 + dt * 16 + lm] =
                    f2bf(accO[mt][dt][r]);
}

// ---------- Kernel 4: combine splits, normalize (vectorized u16x8) ----------
template<int NSP>
__global__ __launch_bounds__(256)
void k_combine(const u16* __restrict__ opart, const float* __restrict__ lpart,
               u16* __restrict__ obf)
{
    int idx = blockIdx.x * 256 + threadIdx.x;
    int lq = idx >> 9;
    int c8 = (idx & 511) << 3;
    int h = c8 >> 7, d = c8 & 127;
    int kh = h >> 2, rep = h & 3;
    float os[8] = {};
    float ls = 0.f;
    #pragma unroll
    for (int s = 0; s < NSP; s++) {
        size_t b = (((size_t)kh * NSP + s) * 4 + rep) * 64 + lq;
        u16x8 v = *(const u16x8*)&opart[b * 128 + d];
        #pragma unroll
        for (int j = 0; j < 8; j++) os[j] += bf2f(v[j]);
        ls += lpart[b];
    }
    float inv = 1.0f / ls;
    u16x8 o;
    #pragma unroll
    for (int j = 0; j < 8; j++) o[j] = f2bf(os[j] * inv);
    *(u16x8*)&obf[(size_t)lq * 4096 + c8] = o;
}

// ------ Kernel 5: O projection, split-K, 4-deep register-ring pipeline ------
__global__ __launch_bounds__(256)
void k_oproj(const u16* __restrict__ obf, const float* __restrict__ Wo,
             float* __restrict__ parto)
{
    constexpr int NKT = 4096 / OSPLIT / 64;    // 8
    const int col0 = blockIdx.x * 32;
    const int osp = blockIdx.y;
    const int ks0 = osp * (4096 / OSPLIT);

    __shared__ __align__(16) u16 As[2][64][72];
    __shared__ __align__(16) u16 Bs[2][32 * 64];

    const int t = threadIdx.x;
    const int w = t >> 6, l = t & 63;
    const int lm = l & 15, lg = l >> 4;

    const int arow = t >> 3;
    const int ac8 = (t & 7) << 3;
    const int bk = (t >> 3) << 1;
    const int bn4 = (t & 7) << 2;

    u16x8 pa[4][2];
    f32x4 pb[4][2];
    f32x4 acc[2] = {};

    #define OP_LOAD(slot_, kt_)                                                \
    {                                                                          \
        const int kg = ks0 + (kt_) * 64;                                       \
        pa[slot_][0] = *(const u16x8*)&obf[(size_t)arow * 4096 + kg + ac8];    \
        pa[slot_][1] = *(const u16x8*)&obf[(size_t)(arow + 32) * 4096 + kg + ac8]; \
        pb[slot_][0] = *(const f32x4*)&Wo[(size_t)(kg + bk) * 4096 + col0 + bn4]; \
        pb[slot_][1] = *(const f32x4*)&Wo[(size_t)(kg + bk + 1) * 4096 + col0 + bn4]; \
    }
    #define OP_STORE(buf_, slot_)                                              \
    {                                                                          \
        *(u16x8*)&As[buf_][arow][ac8] = pa[slot_][0];                          \
        *(u16x8*)&As[buf_][arow + 32][ac8] = pa[slot_][1];                     \
        _Pragma("unroll")                                                      \
        for (int j = 0; j < 4; j++) {                                          \
            int n = bn4 + j;                                                   \
            int idx = n * 64 + (bk ^ (((n >> 1) & 7) << 3));                   \
            ushort2 v2; v2.x = f2bf(pb[slot_][0][j]); v2.y = f2bf(pb[slot_][1][j]); \
            *(ushort2*)&Bs[buf_][idx] = v2;                                    \
        }                                                                      \
    }

    OP_LOAD(0, 0);
    OP_LOAD(1, 1);
    OP_LOAD(2, 2);
    OP_LOAD(3, 3);
    OP_STORE(0, 0);
    __syncthreads();

    #pragma unroll
    for (int kt = 0; kt < NKT; kt++) {
        const int cur = kt & 1;
        if (kt + 4 < NKT) OP_LOAD(kt & 3, kt + 4);
        if (kt + 1 < NKT) OP_STORE(cur ^ 1, (kt + 1) & 3);
        #pragma unroll
        for (int ks = 0; ks < 2; ks++) {
            const int koff = ks * 32 + lg * 8;
            bf16x8 a0 = *(const bf16x8*)&As[cur][w * 16 + lm][koff];
            #pragma unroll
            for (int nt = 0; nt < 2; nt++) {
                int n = nt * 16 + lm;
                bf16x8 b = *(const bf16x8*)
                    &Bs[cur][n * 64 + (koff ^ (((n >> 1) & 7) << 3))];
                acc[nt] = mfma16(a0, b, acc[nt]);
            }
        }
        if (kt + 1 < NKT) __syncthreads();
    }
    #pragma unroll
    for (int nt = 0; nt < 2; nt++)
        #pragma unroll
        for (int r = 0; r < 4; r++)
            parto[((size_t)osp * 64 + w * 16 + lg * 4 + r) * 4096 +
                  col0 + nt * 16 + lm] = acc[nt][r];
    #undef OP_LOAD
    #undef OP_STORE
}

// ------------------- Kernel 6: sum O-proj split-K partials ------------------
__global__ __launch_bounds__(256)
void k_osum(const float* __restrict__ parto, float* __restrict__ out0)
{
    int idx = blockIdx.x * 256 + threadIdx.x;
    float s = 0.f;
    #pragma unroll
    for (int o = 0; o < OSPLIT; o++)
        s += parto[(size_t)o * 262144 + idx];
    out0[idx] = s;
}

extern "C" void kernel_launch(void* const* d_in, const int* in_sizes, int n_in,
                              void* d_out, int out_size, void* d_ws, size_t ws_size,
                              hipStream_t stream)
{
    (void)in_sizes; (void)n_in; (void)out_size; (void)ws_size;
    const float* x      = (const float*)d_in[0];
    const float* xctx   = (const float*)d_in[1];
    const float* cosq   = (const float*)d_in[2];
    const float* sinq   = (const float*)d_in[3];
    const float* cosk   = (const float*)d_in[4];
    const float* sink   = (const float*)d_in[5];
    const float* cacheK = (const float*)d_in[6];
    const float* cacheV = (const float*)d_in[7];
    const float* Wq     = (const float*)d_in[9];
    const float* Wk     = (const float*)d_in[10];
    const float* Wv     = (const float*)d_in[11];
    const float* Wo     = (const float*)d_in[12];
    const float* qnw    = (const float*)d_in[13];
    const float* knw    = (const float*)d_in[14];

    float* out0 = (float*)d_out;               // o@Wo (64, 4096)
    float* out1 = out0 + 262144;               // k (8, 128, 128)
    float* out2 = out1 + 131072;               // v (8, 128, 128)

    // Layout — total 26,738,688 B (extent proven writable in R7-R16).
    char* ws = (char*)d_ws;
    float* part  = (float*)(ws + 0);           // 4 x 128 x 6144 f32 = 12.6 MB
    u16*   kc    = (u16*)(ws + 0);
    u16*   vt    = (u16*)(ws + 8650752);
    u16*   opart = (u16*)(ws + 17301504);
    float* lpart = (float*)(ws + 23068672);
    float* parto = (float*)(ws + 0);
    u16*   fragA = (u16*)(ws + 25165824);
    u16*   qb    = (u16*)(ws + 25165824);
    u16*   kb    = (u16*)(ws + 25165824 + 524288);
    u16*   vb    = (u16*)(ws + 25165824 + 786432);
    u16*   obf   = (u16*)(ws + 25165824 + 1048576);

    k_prep<<<256, 256, 0, stream>>>(x, xctx, fragA);
    k_qkv<KSPLIT><<<dim3(192, KSPLIT), 256, 0, stream>>>(fragA, Wq, Wk, Wv, part);
    k_normrope<KSPLIT><<<1024, 256, 0, stream>>>(part, cosq, sinq, cosk, sink,
                                                 qnw, knw, qb, kb, out1, out2, vb);
    k_prepkv<<<2640, 256, 0, stream>>>(cacheK, cacheV, kb, vb, kc, vt);
    k_attn<<<dim3(NSPLIT, 8, 2), 256, 0, stream>>>(qb, kc, vt, opart, lpart);
    k_combine<NSPLIT><<<128, 256, 0, stream>>>(opart, lpart, obf);
    k_oproj<<<dim3(128, OSPLIT), 256, 0, stream>>>(obf, Wo, parto);
    k_osum<<<1024, 256, 0, stream>>>(parto, out0);
}